// Round 13
// baseline (914.195 us; speedup 1.0000x reference)
//
#include <hip/hip_runtime.h>
#include <stdint.h>
#include <math.h>

constexpr int BB = 16;      // batch
constexpr int NN = 4096;    // points per batch
constexpr int SS = 1024;    // centroids (N_CENTROIDS)
constexpr int KK = 32;      // NSAMPLES
constexpr int C3 = 128;     // mlp1
constexpr float R2 = 0.25f; // RADIUS^2
constexpr int STAT_BLOCKS = 2048;  // blocks for stats kernels (8 groups each)

typedef float v2f __attribute__((ext_vector_type(2)));

// exact-order (a0*a0 + a1*a1) + a2*a2, no fma contraction (matches np sum over 3)
__device__ __forceinline__ float sumsq3(float x, float y, float z) {
#pragma clang fp contract(off)
  return (x * x + y * y) + z * z;
}

// packed elementwise version — identical per-element op order
__device__ __forceinline__ v2f sumsq3p(v2f x, v2f y, v2f z) {
#pragma clang fp contract(off)
  return (x * x + y * y) + z * z;
}

// exact-order GEMM-form squared distance: (aa + bb) - 2*((cx*px+cy*py)+cz*pz)
__device__ __forceinline__ float ball_d(float aa, float bb, float cx, float cy,
                                        float cz, float px, float py, float pz) {
#pragma clang fp contract(off)
  float ab = (cx * px + cy * py) + cz * pz;
  return (aa + bb) - 2.0f * ab;
}

__device__ __forceinline__ unsigned long long u64max(unsigned long long a,
                                                     unsigned long long b) {
  return a > b ? a : b;
}

// one DPP max step on a u64 key (VALU pipe, ~4cyc latency vs ~35 for LDS shuffles)
#define DPP_KEY_STEP(CTRL, k)                                                  \
  {                                                                            \
    int lo_ = (int)(unsigned)(k);                                              \
    int hi_ = (int)(unsigned)((k) >> 32);                                      \
    int slo_ = __builtin_amdgcn_update_dpp(0, lo_, (CTRL), 0xf, 0xf, true);    \
    int shi_ = __builtin_amdgcn_update_dpp(0, hi_, (CTRL), 0xf, 0xf, true);    \
    unsigned long long o_ =                                                    \
        ((unsigned long long)(unsigned)shi_ << 32) | (unsigned)(unsigned)slo_; \
    (k) = u64max((k), o_);                                                     \
  }

// f32 quad max/min via DPP (fmax/fmin commutative+associative -> exact)
#define DPP_MAXF(CTRL, v)                                                      \
  {                                                                            \
    int s_ = __builtin_amdgcn_update_dpp(0, __float_as_int(v), (CTRL), 0xf,    \
                                         0xf, true);                           \
    (v) = fmaxf((v), __int_as_float(s_));                                      \
  }
#define DPP_MINF(CTRL, v)                                                      \
  {                                                                            \
    int s_ = __builtin_amdgcn_update_dpp(0, __float_as_int(v), (CTRL), 0xf,    \
                                         0xf, true);                           \
    (v) = fminf((v), __int_as_float(s_));                                      \
  }

// read the u64 key of a fixed lane (wave-uniform result in SGPRs)
__device__ __forceinline__ unsigned long long readlane_key(unsigned lo,
                                                           unsigned hi,
                                                           int lane) {
  unsigned l = (unsigned)__builtin_amdgcn_readlane((int)lo, lane);
  unsigned h = (unsigned)__builtin_amdgcn_readlane((int)hi, lane);
  return ((unsigned long long)h << 32) | l;
}

// ---- FPS: 256 thr, packed-f32 dist loop, DPP row-max + readlane fold, barrier sync ----
__global__ __launch_bounds__(256) void k_fps(const float* __restrict__ x,
                                             float* __restrict__ outc,
                                             float* __restrict__ aa) {
  __shared__ float4 xs4[NN];                // packed xyz: 1-load broadcast
  __shared__ unsigned long long wkey[2][4];
  __shared__ int farhist[SS];
  int b = blockIdx.x, t = threadIdx.x;
  const float* xb = x + (size_t)b * NN * 3;
  v2f px2[8], py2[8], pz2[8], dm2[8];
#pragma unroll
  for (int i = 0; i < 8; ++i) {
    int n0 = t + (2 * i) * 256, n1 = t + (2 * i + 1) * 256;
    float a0 = xb[3 * n0], a1 = xb[3 * n0 + 1], a2 = xb[3 * n0 + 2];
    float b0 = xb[3 * n1], b1 = xb[3 * n1 + 1], b2 = xb[3 * n1 + 2];
    px2[i] = (v2f){a0, b0}; py2[i] = (v2f){a1, b1}; pz2[i] = (v2f){a2, b2};
    dm2[i] = (v2f){1e10f, 1e10f};
    xs4[n0] = make_float4(a0, a1, a2, 0.f);
    xs4[n1] = make_float4(b0, b1, b2, 0.f);
  }
  if (t == 0) farhist[0] = 0;
  __syncthreads();
  int far = 0;
  int w = t >> 6;
  unsigned base = (unsigned)(NN - 1 - t);  // blo = base - (bj<<8)
  for (int it = 1; it < SS; ++it) {
    float4 c4 = xs4[far];
    v2f cx2 = (v2f){c4.x, c4.x}, cy2 = (v2f){c4.y, c4.y}, cz2 = (v2f){c4.z, c4.z};
    float best = -1.0f;
    int bj = 0;
#pragma unroll
    for (int i = 0; i < 8; ++i) {
      v2f dx = px2[i] - cx2, dy = py2[i] - cy2, dz = pz2[i] - cz2;
      v2f d = sumsq3p(dx, dy, dz);      // packed mul/add, per-element exact order
      v2f dm = dm2[i];
      dm.x = fminf(dm.x, d.x);
      dm.y = fminf(dm.y, d.y);
      dm2[i] = dm;
      // j ascending == n ascending (n = t + j*256); strict > keeps earliest n
      if (dm.x > best) { best = dm.x; bj = 2 * i; }
      if (dm.y > best) { best = dm.y; bj = 2 * i + 1; }
    }
    unsigned blo = base - ((unsigned)bj << 8);  // NN-1-n: max() picks smallest n on ties
    // dists >= 0 so f32-bit order == uint order
    unsigned long long key =
        ((unsigned long long)__float_as_uint(best) << 32) | blo;
    // row(16)-max via DPP: quad_perm xor1, xor2, row_ror:4, row_ror:8
    DPP_KEY_STEP(0xB1, key);   // quad_perm [1,0,3,2]  == xor 1
    DPP_KEY_STEP(0x4E, key);   // quad_perm [2,3,0,1]  == xor 2
    DPP_KEY_STEP(0x124, key);  // row_ror:4  (covers quad q+1)
    DPP_KEY_STEP(0x128, key);  // row_ror:8  (covers quads q+2,q+3)
    // wave fold: rows live in lanes 0/16/32/48 -> SGPRs (no LDS shuffles)
    {
      unsigned klo = (unsigned)key, khi = (unsigned)(key >> 32);
      unsigned long long r0 = readlane_key(klo, khi, 0);
      unsigned long long r1 = readlane_key(klo, khi, 16);
      unsigned long long r2 = readlane_key(klo, khi, 32);
      unsigned long long r3 = readlane_key(klo, khi, 48);
      key = u64max(u64max(r0, r1), u64max(r2, r3));  // wave-uniform
    }
    int buf = it & 1;
    if ((t & 63) == 0) wkey[buf][w] = key;
    __syncthreads();
    unsigned long long k0 = wkey[buf][0], k1 = wkey[buf][1];
    unsigned long long k2 = wkey[buf][2], k3 = wkey[buf][3];
    unsigned long long kk = u64max(u64max(k0, k1), u64max(k2, k3));
    far = NN - 1 - (int)(unsigned)(kk & 0xffffffffu);
    if (t == 0) farhist[it] = far;
  }
  __syncthreads();
  // fused gather: centroids straight from LDS (bit-exact copies of x)
  for (int i = t; i < SS; i += 256) {
    int n = farhist[i];
    float4 c4 = xs4[n];
    int gi = b * SS + i;
    outc[3 * gi] = c4.x; outc[3 * gi + 1] = c4.y; outc[3 * gi + 2] = c4.z;
    aa[gi] = sumsq3(c4.x, c4.y, c4.z);
  }
}

// ---- fused ball query + BN1 stats: 8 groups/block; idx kept in LDS ----
__global__ __launch_bounds__(256) void k_ballstats1(
    const float* __restrict__ x, const float* __restrict__ pts,
    const float* __restrict__ cent, const float* __restrict__ aa,
    const float* __restrict__ w1, const float* __restrict__ b1,
    int* __restrict__ idx, float* __restrict__ partial1) {
  __shared__ int sidx[8][KK];
  __shared__ float feat[KK][6];
  __shared__ float red[4][64][2];
  int t = threadIdx.x;
  int w = t >> 6, lane = t & 63;
  // ---- phase 1: ball; wave w handles groups {8*blk+w, 8*blk+w+4} ----
  for (int qq = 0; qq < 2; ++qq) {
    int q = w + qq * 4;
    int g = blockIdx.x * 8 + q;
    int b = g >> 10;
    const float* xb = x + (size_t)b * NN * 3;
    float cx = cent[3 * g], cy = cent[3 * g + 1], cz = cent[3 * g + 2];
    float a = aa[g];
    int* gout = idx + (size_t)g * KK;
    int found = 0, firstN = 0;
    for (int c0 = 0; c0 < NN && found < KK; c0 += 64) {
      int n = c0 + lane;
      float px = xb[3 * n], py = xb[3 * n + 1], pz = xb[3 * n + 2];
      float pb = sumsq3(px, py, pz);   // identical ops to reference's bb
      float d = ball_d(a, pb, cx, cy, cz, px, py, pz);
      bool pred = (d <= R2);  // reference excludes d > r^2
      unsigned long long m = __ballot(pred);
      if (found == 0 && m) firstN = c0 + (__ffsll((unsigned long long)m) - 1);
      if (pred) {
        int pos = found + __popcll(m & ((1ull << lane) - 1ull));
        if (pos < KK) { gout[pos] = n; sidx[q][pos] = n; }
      }
      found += __popcll(m);
    }
    if (lane == 0 && found < KK) {
      for (int k = found; k < KK; ++k) { gout[k] = firstN; sidx[q][k] = firstN; }
    }
  }
  __syncthreads();  // sidx complete
  // ---- phase 2: conv1 per-channel sum/sumsq over the 8 groups ----
  int c = t & 63, kq = t >> 6;
  float wv[6];
#pragma unroll
  for (int j = 0; j < 6; ++j) wv[j] = w1[c * 6 + j];
  float bias = b1[c];
  float sum = 0.f, sq = 0.f;
  for (int gi = 0; gi < 8; ++gi) {
    int g = blockIdx.x * 8 + gi;
    int b = g >> 10;
    if (t < KK) {
      int n = sidx[gi][t];
      const float* p = x + ((size_t)b * NN + n) * 3;
      feat[t][0] = p[0] - cent[3 * g];
      feat[t][1] = p[1] - cent[3 * g + 1];
      feat[t][2] = p[2] - cent[3 * g + 2];
      const float* q = pts + ((size_t)b * NN + n) * 3;
      feat[t][3] = q[0];
      feat[t][4] = q[1];
      feat[t][5] = q[2];
    }
    __syncthreads();
    for (int k = kq * 8; k < kq * 8 + 8; ++k) {
      float a = bias;
#pragma unroll
      for (int j = 0; j < 6; ++j) a += wv[j] * feat[k][j];
      sum += a;
      sq += a * a;
    }
    __syncthreads();
  }
  red[kq][c][0] = sum;
  red[kq][c][1] = sq;
  __syncthreads();
  if (t < 64) {
    float s = ((red[0][t][0] + red[1][t][0]) + red[2][t][0]) + red[3][t][0];
    float q = ((red[0][t][1] + red[1][t][1]) + red[2][t][1]) + red[3][t][1];
    partial1[(size_t)(blockIdx.x * 64 + t) * 2] = s;
    partial1[(size_t)(blockIdx.x * 64 + t) * 2 + 1] = q;
  }
}

// ---------------- finalize BN1 scale/shift (16-way parallel over blocks) ----------------
__global__ void k_red1(const float* __restrict__ partial1,
                       const float* __restrict__ gamma, const float* __restrict__ beta,
                       float* __restrict__ sc1) {
  __shared__ double rd[64][16][2];
  int t = threadIdx.x;  // 1024
  int c = t & 63, q = t >> 6;  // q in 0..15
  double s = 0.0, qq = 0.0;
  for (int blk = q * 128; blk < q * 128 + 128; ++blk) {
    s += partial1[(size_t)(blk * 64 + c) * 2];
    qq += partial1[(size_t)(blk * 64 + c) * 2 + 1];
  }
  rd[c][q][0] = s; rd[c][q][1] = qq;
  __syncthreads();
  if (t < 64) {
    double S = 0.0, Q = 0.0;
#pragma unroll
    for (int i = 0; i < 16; ++i) { S += rd[t][i][0]; Q += rd[t][i][1]; }
    const double cnt = (double)BB * KK * SS;
    double mean = S / cnt;
    double var = Q / cnt - mean * mean;
    float scale = gamma[t] * (float)(1.0 / sqrt(var + 1e-5));
    float shift = beta[t] - (float)mean * scale;
    sc1[t] = scale;
    sc1[64 + t] = shift;
  }
}

// -------- stats for BN2 + per-group max/min of pre-BN conv2 (for maxpool) --------
// w2 read from global (L1/L2-resident 32KB); LDS ~15KB -> ~6 blocks/CU.
// minmax via quad DPP (fmax/fmin exact) -> barrier C removed.
__global__ __launch_bounds__(256) void k_stats2(
    const float* __restrict__ x, const float* __restrict__ pts,
    const float* __restrict__ cent, const int* __restrict__ idx,
    const float* __restrict__ w1, const float* __restrict__ b1,
    const float* __restrict__ sc1, const float* __restrict__ w2,
    const float* __restrict__ b2, float* __restrict__ partial2,
    float* __restrict__ gmax, float* __restrict__ gmin) {
  __shared__ float feat[KK][6];
  __shared__ float vT[64][36];        // [c1][k] conv1 output, padded rows
  __shared__ float red[C3][4][2];
  int t = threadIdx.x;
  int c1 = t & 63, kq = t >> 6;
  int c2p = t >> 2, ks = t & 3;   // output rows {c2p, c2p+64}, k in [ks*8, ks*8+8)
  const float4* w2a4 = (const float4*)(w2 + c2p * 64);
  const float4* w2b4 = (const float4*)(w2 + (c2p + 64) * 64);
  float w1r[6];
#pragma unroll
  for (int j = 0; j < 6; ++j) w1r[j] = w1[c1 * 6 + j];
  float bias1 = b1[c1];
  float scale1 = sc1[c1], shift1 = sc1[64 + c1];
  float bias2a = b2[c2p], bias2b = b2[c2p + 64];
  float sumA = 0.f, sqA = 0.f, sumB = 0.f, sqB = 0.f;
  for (int gi = 0; gi < 8; ++gi) {
    int g = blockIdx.x * 8 + gi;
    int b = g >> 10;
    if (t < KK) {
      int n = idx[(size_t)g * KK + t];
      const float* p = x + ((size_t)b * NN + n) * 3;
      feat[t][0] = p[0] - cent[3 * g];
      feat[t][1] = p[1] - cent[3 * g + 1];
      feat[t][2] = p[2] - cent[3 * g + 2];
      const float* q = pts + ((size_t)b * NN + n) * 3;
      feat[t][3] = q[0];
      feat[t][4] = q[1];
      feat[t][5] = q[2];
    }
    __syncthreads();  // (A) feat ready; guards vT overwrite vs prev conv2 readers
    for (int k = kq * 8; k < kq * 8 + 8; ++k) {
      float a = bias1;
#pragma unroll
      for (int j = 0; j < 6; ++j) a += w1r[j] * feat[k][j];
      vT[c1][k] = fmaxf(0.f, a * scale1 + shift1);
    }
    __syncthreads();  // (B) vT ready
    float accA[8] = {0, 0, 0, 0, 0, 0, 0, 0};
    float accB[8] = {0, 0, 0, 0, 0, 0, 0, 0};
#pragma unroll 4
    for (int c0 = 0; c0 < 64; c0 += 4) {
      float4 wa4 = w2a4[c0 >> 2];
      float4 wb4 = w2b4[c0 >> 2];
#pragma unroll
      for (int cc = 0; cc < 4; ++cc) {
        int c = c0 + cc;
        float4 v0 = *(const float4*)&vT[c][ks * 8];
        float4 v1 = *(const float4*)&vT[c][ks * 8 + 4];
        float wa = (cc == 0 ? wa4.x : cc == 1 ? wa4.y : cc == 2 ? wa4.z : wa4.w);
        float wb = (cc == 0 ? wb4.x : cc == 1 ? wb4.y : cc == 2 ? wb4.z : wb4.w);
        accA[0] += wa * v0.x; accA[1] += wa * v0.y; accA[2] += wa * v0.z; accA[3] += wa * v0.w;
        accA[4] += wa * v1.x; accA[5] += wa * v1.y; accA[6] += wa * v1.z; accA[7] += wa * v1.w;
        accB[0] += wb * v0.x; accB[1] += wb * v0.y; accB[2] += wb * v0.z; accB[3] += wb * v0.w;
        accB[4] += wb * v1.x; accB[5] += wb * v1.y; accB[6] += wb * v1.z; accB[7] += wb * v1.w;
      }
    }
    float mA = -1e30f, mB = -1e30f, nA = 1e30f, nB = 1e30f;
#pragma unroll
    for (int i = 0; i < 8; ++i) {
      float a = accA[i] + bias2a;
      sumA += a; sqA += a * a;
      mA = fmaxf(mA, a); nA = fminf(nA, a);
      float c_ = accB[i] + bias2b;
      sumB += c_; sqB += c_ * c_;
      mB = fmaxf(mB, c_); nB = fminf(nB, c_);
    }
    // quad reduce over ks (the 4 threads of a quad) via DPP — exact for fmax/fmin
    DPP_MAXF(0xB1, mA); DPP_MAXF(0x4E, mA);
    DPP_MINF(0xB1, nA); DPP_MINF(0x4E, nA);
    DPP_MAXF(0xB1, mB); DPP_MAXF(0x4E, mB);
    DPP_MINF(0xB1, nB); DPP_MINF(0x4E, nB);
    if (ks == 0) {
      gmax[(size_t)g * C3 + c2p] = mA;
      gmin[(size_t)g * C3 + c2p] = nA;
      gmax[(size_t)g * C3 + c2p + 64] = mB;
      gmin[(size_t)g * C3 + c2p + 64] = nB;
    }
  }
  red[c2p][ks][0] = sumA;      red[c2p][ks][1] = sqA;
  red[c2p + 64][ks][0] = sumB; red[c2p + 64][ks][1] = sqB;
  __syncthreads();
  if (t < C3) {
    float s = ((red[t][0][0] + red[t][1][0]) + red[t][2][0]) + red[t][3][0];
    float q = ((red[t][0][1] + red[t][1][1]) + red[t][2][1]) + red[t][3][1];
    partial2[(size_t)(blockIdx.x * 128 + t) * 2] = s;
    partial2[(size_t)(blockIdx.x * 128 + t) * 2 + 1] = q;
  }
}

// ---------------- finalize BN2 scale/shift (8-way parallel over blocks) ----------------
__global__ void k_red2(const float* __restrict__ partial2,
                       const float* __restrict__ gamma, const float* __restrict__ beta,
                       float* __restrict__ sc2) {
  __shared__ double rd[128][8][2];
  int t = threadIdx.x;  // 1024
  int c = t & 127, q = t >> 7;  // q in 0..7
  double s = 0.0, qq = 0.0;
  for (int blk = q * 256; blk < q * 256 + 256; ++blk) {
    s += partial2[(size_t)(blk * 128 + c) * 2];
    qq += partial2[(size_t)(blk * 128 + c) * 2 + 1];
  }
  rd[c][q][0] = s; rd[c][q][1] = qq;
  __syncthreads();
  if (t < 128) {
    double S = 0.0, Q = 0.0;
#pragma unroll
    for (int i = 0; i < 8; ++i) { S += rd[t][i][0]; Q += rd[t][i][1]; }
    const double cnt = (double)BB * KK * SS;
    double mean = S / cnt;
    double var = Q / cnt - mean * mean;
    float scale = gamma[t] * (float)(1.0 / sqrt(var + 1e-5));
    float shift = beta[t] - (float)mean * scale;
    sc2[t] = scale;
    sc2[128 + t] = shift;
  }
}

// -------- final: affine+relu on the pooled pre-BN max (min if scale<0) --------
// max_k relu(a_k*s+t) == relu((s>=0 ? max_k a : min_k a)*s+t)  exactly (monotone f32 ops)
__global__ void k_final2(const float* __restrict__ gmin,
                         const float* __restrict__ sc2, float* __restrict__ outp) {
  int i = blockIdx.x * blockDim.x + threadIdx.x;  // over BB*SS*C3, gmax lives in outp
  if (i >= BB * SS * C3) return;
  int c = i & (C3 - 1);
  float scale = sc2[c], shift = sc2[C3 + c];
  float a = (scale >= 0.f) ? outp[i] : gmin[i];
  outp[i] = fmaxf(0.f, a * scale + shift);
}

extern "C" void kernel_launch(void* const* d_in, const int* in_sizes, int n_in,
                              void* d_out, int out_size, void* d_ws, size_t ws_size,
                              hipStream_t stream) {
  const float* x      = (const float*)d_in[0];
  const float* pts    = (const float*)d_in[1];
  const float* w1     = (const float*)d_in[2];
  const float* b1     = (const float*)d_in[3];
  const float* gamma1 = (const float*)d_in[4];
  const float* beta1  = (const float*)d_in[5];
  const float* w2     = (const float*)d_in[6];
  const float* b2     = (const float*)d_in[7];
  const float* gamma2 = (const float*)d_in[8];
  const float* beta2  = (const float*)d_in[9];

  float* out_cent = (float*)d_out;                       // [B,S,3]
  float* out_feat = (float*)d_out + (size_t)BB * SS * 3; // [B,S,128] (doubles as gmax)

  char* w = (char*)d_ws;
  float* aa    = (float*)w; w += (size_t)BB * SS * 4;
  int* idx     = (int*)w;   w += (size_t)BB * SS * KK * 4;
  float* p1    = (float*)w; w += (size_t)STAT_BLOCKS * 64 * 2 * 4;
  float* p2    = (float*)w; w += (size_t)STAT_BLOCKS * 128 * 2 * 4;
  float* sc1   = (float*)w; w += 64 * 2 * 4;
  float* sc2   = (float*)w; w += 128 * 2 * 4;
  float* gmin  = (float*)w; w += (size_t)BB * SS * C3 * 4;  // 8 MB

  k_fps<<<BB, 256, 0, stream>>>(x, out_cent, aa);
  k_ballstats1<<<STAT_BLOCKS, 256, 0, stream>>>(x, pts, out_cent, aa, w1, b1,
                                                idx, p1);
  k_red1<<<1, 1024, 0, stream>>>(p1, gamma1, beta1, sc1);
  k_stats2<<<STAT_BLOCKS, 256, 0, stream>>>(x, pts, out_cent, idx, w1, b1, sc1,
                                            w2, b2, p2, out_feat, gmin);
  k_red2<<<1, 1024, 0, stream>>>(p2, gamma2, beta2, sc2);
  k_final2<<<(BB * SS * C3 + 255) / 256, 256, 0, stream>>>(gmin, sc2, out_feat);
}

// Round 14
// 893.975 us; speedup vs baseline: 1.0226x; 1.0226x over previous
//
#include <hip/hip_runtime.h>
#include <stdint.h>
#include <math.h>

constexpr int BB = 16;      // batch
constexpr int NN = 4096;    // points per batch
constexpr int SS = 1024;    // centroids (N_CENTROIDS)
constexpr int KK = 32;      // NSAMPLES
constexpr int C3 = 128;     // mlp1
constexpr float R2 = 0.25f; // RADIUS^2
constexpr int STAT_BLOCKS = 2048;  // blocks for stats kernels (8 groups each)

typedef float v2f __attribute__((ext_vector_type(2)));

// exact-order (a0*a0 + a1*a1) + a2*a2, no fma contraction (matches np sum over 3)
__device__ __forceinline__ float sumsq3(float x, float y, float z) {
#pragma clang fp contract(off)
  return (x * x + y * y) + z * z;
}

// packed elementwise version — identical per-element op order
__device__ __forceinline__ v2f sumsq3p(v2f x, v2f y, v2f z) {
#pragma clang fp contract(off)
  return (x * x + y * y) + z * z;
}

// exact-order GEMM-form squared distance: (aa + bb) - 2*((cx*px+cy*py)+cz*pz)
__device__ __forceinline__ float ball_d(float aa, float bb, float cx, float cy,
                                        float cz, float px, float py, float pz) {
#pragma clang fp contract(off)
  float ab = (cx * px + cy * py) + cz * pz;
  return (aa + bb) - 2.0f * ab;
}

__device__ __forceinline__ unsigned long long u64max(unsigned long long a,
                                                     unsigned long long b) {
  return a > b ? a : b;
}

// one DPP max step on a u64 key (VALU pipe, ~4cyc latency vs ~35 for LDS shuffles)
#define DPP_KEY_STEP(CTRL, k)                                                  \
  {                                                                            \
    int lo_ = (int)(unsigned)(k);                                              \
    int hi_ = (int)(unsigned)((k) >> 32);                                      \
    int slo_ = __builtin_amdgcn_update_dpp(0, lo_, (CTRL), 0xf, 0xf, true);    \
    int shi_ = __builtin_amdgcn_update_dpp(0, hi_, (CTRL), 0xf, 0xf, true);    \
    unsigned long long o_ =                                                    \
        ((unsigned long long)(unsigned)shi_ << 32) | (unsigned)(unsigned)slo_; \
    (k) = u64max((k), o_);                                                     \
  }

// read the u64 key of a fixed lane (wave-uniform result in SGPRs)
__device__ __forceinline__ unsigned long long readlane_key(unsigned lo,
                                                           unsigned hi,
                                                           int lane) {
  unsigned l = (unsigned)__builtin_amdgcn_readlane((int)lo, lane);
  unsigned h = (unsigned)__builtin_amdgcn_readlane((int)hi, lane);
  return ((unsigned long long)h << 32) | l;
}

// ---- FPS: 256 thr, packed-f32 dist loop, DPP row-max + readlane fold, barrier sync ----
__global__ __launch_bounds__(256) void k_fps(const float* __restrict__ x,
                                             float* __restrict__ outc,
                                             float* __restrict__ aa) {
  __shared__ float4 xs4[NN];                // packed xyz: 1-load broadcast
  __shared__ unsigned long long wkey[2][4];
  __shared__ int farhist[SS];
  int b = blockIdx.x, t = threadIdx.x;
  const float* xb = x + (size_t)b * NN * 3;
  v2f px2[8], py2[8], pz2[8], dm2[8];
#pragma unroll
  for (int i = 0; i < 8; ++i) {
    int n0 = t + (2 * i) * 256, n1 = t + (2 * i + 1) * 256;
    float a0 = xb[3 * n0], a1 = xb[3 * n0 + 1], a2 = xb[3 * n0 + 2];
    float b0 = xb[3 * n1], b1 = xb[3 * n1 + 1], b2 = xb[3 * n1 + 2];
    px2[i] = (v2f){a0, b0}; py2[i] = (v2f){a1, b1}; pz2[i] = (v2f){a2, b2};
    dm2[i] = (v2f){1e10f, 1e10f};
    xs4[n0] = make_float4(a0, a1, a2, 0.f);
    xs4[n1] = make_float4(b0, b1, b2, 0.f);
  }
  if (t == 0) farhist[0] = 0;
  __syncthreads();
  int far = 0;
  int w = t >> 6;
  unsigned base = (unsigned)(NN - 1 - t);  // blo = base - (bj<<8)
  for (int it = 1; it < SS; ++it) {
    float4 c4 = xs4[far];
    v2f cx2 = (v2f){c4.x, c4.x}, cy2 = (v2f){c4.y, c4.y}, cz2 = (v2f){c4.z, c4.z};
    float best = -1.0f;
    int bj = 0;
#pragma unroll
    for (int i = 0; i < 8; ++i) {
      v2f dx = px2[i] - cx2, dy = py2[i] - cy2, dz = pz2[i] - cz2;
      v2f d = sumsq3p(dx, dy, dz);      // packed mul/add, per-element exact order
      v2f dm = dm2[i];
      dm.x = fminf(dm.x, d.x);
      dm.y = fminf(dm.y, d.y);
      dm2[i] = dm;
      // j ascending == n ascending (n = t + j*256); strict > keeps earliest n
      if (dm.x > best) { best = dm.x; bj = 2 * i; }
      if (dm.y > best) { best = dm.y; bj = 2 * i + 1; }
    }
    unsigned blo = base - ((unsigned)bj << 8);  // NN-1-n: max() picks smallest n on ties
    // dists >= 0 so f32-bit order == uint order
    unsigned long long key =
        ((unsigned long long)__float_as_uint(best) << 32) | blo;
    // row(16)-max via DPP: quad_perm xor1, xor2, row_ror:4, row_ror:8
    DPP_KEY_STEP(0xB1, key);   // quad_perm [1,0,3,2]  == xor 1
    DPP_KEY_STEP(0x4E, key);   // quad_perm [2,3,0,1]  == xor 2
    DPP_KEY_STEP(0x124, key);  // row_ror:4  (covers quad q+1)
    DPP_KEY_STEP(0x128, key);  // row_ror:8  (covers quads q+2,q+3)
    // wave fold: rows live in lanes 0/16/32/48 -> SGPRs (no LDS shuffles)
    {
      unsigned klo = (unsigned)key, khi = (unsigned)(key >> 32);
      unsigned long long r0 = readlane_key(klo, khi, 0);
      unsigned long long r1 = readlane_key(klo, khi, 16);
      unsigned long long r2 = readlane_key(klo, khi, 32);
      unsigned long long r3 = readlane_key(klo, khi, 48);
      key = u64max(u64max(r0, r1), u64max(r2, r3));  // wave-uniform
    }
    int buf = it & 1;
    if ((t & 63) == 0) wkey[buf][w] = key;
    __syncthreads();
    unsigned long long k0 = wkey[buf][0], k1 = wkey[buf][1];
    unsigned long long k2 = wkey[buf][2], k3 = wkey[buf][3];
    unsigned long long kk = u64max(u64max(k0, k1), u64max(k2, k3));
    far = NN - 1 - (int)(unsigned)(kk & 0xffffffffu);
    if (t == 0) farhist[it] = far;
  }
  __syncthreads();
  // fused gather: centroids straight from LDS (bit-exact copies of x)
  for (int i = t; i < SS; i += 256) {
    int n = farhist[i];
    float4 c4 = xs4[n];
    int gi = b * SS + i;
    outc[3 * gi] = c4.x; outc[3 * gi + 1] = c4.y; outc[3 * gi + 2] = c4.z;
    aa[gi] = sumsq3(c4.x, c4.y, c4.z);
  }
}

// ---- fused ball query + BN1 stats: 8 groups/block; idx kept in LDS ----
__global__ __launch_bounds__(256) void k_ballstats1(
    const float* __restrict__ x, const float* __restrict__ pts,
    const float* __restrict__ cent, const float* __restrict__ aa,
    const float* __restrict__ w1, const float* __restrict__ b1,
    int* __restrict__ idx, float* __restrict__ partial1) {
  __shared__ int sidx[8][KK];
  __shared__ float feat[KK][6];
  __shared__ float red[4][64][2];
  int t = threadIdx.x;
  int w = t >> 6, lane = t & 63;
  // ---- phase 1: ball; wave w handles groups {8*blk+w, 8*blk+w+4} ----
  for (int qq = 0; qq < 2; ++qq) {
    int q = w + qq * 4;
    int g = blockIdx.x * 8 + q;
    int b = g >> 10;
    const float* xb = x + (size_t)b * NN * 3;
    float cx = cent[3 * g], cy = cent[3 * g + 1], cz = cent[3 * g + 2];
    float a = aa[g];
    int* gout = idx + (size_t)g * KK;
    int found = 0, firstN = 0;
    for (int c0 = 0; c0 < NN && found < KK; c0 += 64) {
      int n = c0 + lane;
      float px = xb[3 * n], py = xb[3 * n + 1], pz = xb[3 * n + 2];
      float pb = sumsq3(px, py, pz);   // identical ops to reference's bb
      float d = ball_d(a, pb, cx, cy, cz, px, py, pz);
      bool pred = (d <= R2);  // reference excludes d > r^2
      unsigned long long m = __ballot(pred);
      if (found == 0 && m) firstN = c0 + (__ffsll((unsigned long long)m) - 1);
      if (pred) {
        int pos = found + __popcll(m & ((1ull << lane) - 1ull));
        if (pos < KK) { gout[pos] = n; sidx[q][pos] = n; }
      }
      found += __popcll(m);
    }
    if (lane == 0 && found < KK) {
      for (int k = found; k < KK; ++k) { gout[k] = firstN; sidx[q][k] = firstN; }
    }
  }
  __syncthreads();  // sidx complete
  // ---- phase 2: conv1 per-channel sum/sumsq over the 8 groups ----
  int c = t & 63, kq = t >> 6;
  float wv[6];
#pragma unroll
  for (int j = 0; j < 6; ++j) wv[j] = w1[c * 6 + j];
  float bias = b1[c];
  float sum = 0.f, sq = 0.f;
  for (int gi = 0; gi < 8; ++gi) {
    int g = blockIdx.x * 8 + gi;
    int b = g >> 10;
    if (t < KK) {
      int n = sidx[gi][t];
      const float* p = x + ((size_t)b * NN + n) * 3;
      feat[t][0] = p[0] - cent[3 * g];
      feat[t][1] = p[1] - cent[3 * g + 1];
      feat[t][2] = p[2] - cent[3 * g + 2];
      const float* q = pts + ((size_t)b * NN + n) * 3;
      feat[t][3] = q[0];
      feat[t][4] = q[1];
      feat[t][5] = q[2];
    }
    __syncthreads();
    for (int k = kq * 8; k < kq * 8 + 8; ++k) {
      float a = bias;
#pragma unroll
      for (int j = 0; j < 6; ++j) a += wv[j] * feat[k][j];
      sum += a;
      sq += a * a;
    }
    __syncthreads();
  }
  red[kq][c][0] = sum;
  red[kq][c][1] = sq;
  __syncthreads();
  if (t < 64) {
    float s = ((red[0][t][0] + red[1][t][0]) + red[2][t][0]) + red[3][t][0];
    float q = ((red[0][t][1] + red[1][t][1]) + red[2][t][1]) + red[3][t][1];
    partial1[(size_t)(blockIdx.x * 64 + t) * 2] = s;
    partial1[(size_t)(blockIdx.x * 64 + t) * 2 + 1] = q;
  }
}

// ---------------- finalize BN1 scale/shift (16-way parallel over blocks) ----------------
__global__ void k_red1(const float* __restrict__ partial1,
                       const float* __restrict__ gamma, const float* __restrict__ beta,
                       float* __restrict__ sc1) {
  __shared__ double rd[64][16][2];
  int t = threadIdx.x;  // 1024
  int c = t & 63, q = t >> 6;  // q in 0..15
  double s = 0.0, qq = 0.0;
  for (int blk = q * 128; blk < q * 128 + 128; ++blk) {
    s += partial1[(size_t)(blk * 64 + c) * 2];
    qq += partial1[(size_t)(blk * 64 + c) * 2 + 1];
  }
  rd[c][q][0] = s; rd[c][q][1] = qq;
  __syncthreads();
  if (t < 64) {
    double S = 0.0, Q = 0.0;
#pragma unroll
    for (int i = 0; i < 16; ++i) { S += rd[t][i][0]; Q += rd[t][i][1]; }
    const double cnt = (double)BB * KK * SS;
    double mean = S / cnt;
    double var = Q / cnt - mean * mean;
    float scale = gamma[t] * (float)(1.0 / sqrt(var + 1e-5));
    float shift = beta[t] - (float)mean * scale;
    sc1[t] = scale;
    sc1[64 + t] = shift;
  }
}

// -------- stats for BN2 + per-group max/min of pre-BN conv2 (for maxpool) --------
// w2 staged in LDS (not registers) to keep per-thread VGPRs ~70: no spills.
__global__ __launch_bounds__(256) void k_stats2(
    const float* __restrict__ x, const float* __restrict__ pts,
    const float* __restrict__ cent, const int* __restrict__ idx,
    const float* __restrict__ w1, const float* __restrict__ b1,
    const float* __restrict__ sc1, const float* __restrict__ w2,
    const float* __restrict__ b2, float* __restrict__ partial2,
    float* __restrict__ gmax, float* __restrict__ gmin) {
  __shared__ float feat[KK][6];
  __shared__ float vT[64][36];        // [c1][k] conv1 output, padded rows
  __shared__ float w2sA[64][68];      // w2 rows 0..63   (68: 16B-aligned pad)
  __shared__ float w2sB[64][68];      // w2 rows 64..127
  __shared__ float red[C3][4][2];
  __shared__ float mx[C3][4], mn[C3][4];
  int t = threadIdx.x;
  int c1 = t & 63, kq = t >> 6;
  int c2p = t >> 2, ks = t & 3;   // output rows {c2p, c2p+64}, k in [ks*8, ks*8+8)
  // stage w2 into LDS: thread t loads half of row (t>>1)
  {
    int r = t >> 1, h = (t & 1) * 32;
    float* dst = (r < 64 ? &w2sA[r][h] : &w2sB[r - 64][h]);
    const float* src = w2 + r * 64 + h;
    for (int c = 0; c < 32; ++c) dst[c] = src[c];
  }
  float w1r[6];
#pragma unroll
  for (int j = 0; j < 6; ++j) w1r[j] = w1[c1 * 6 + j];
  float bias1 = b1[c1];
  float scale1 = sc1[c1], shift1 = sc1[64 + c1];
  float bias2a = b2[c2p], bias2b = b2[c2p + 64];
  float sumA = 0.f, sqA = 0.f, sumB = 0.f, sqB = 0.f;
  for (int gi = 0; gi < 8; ++gi) {
    int g = blockIdx.x * 8 + gi;
    int b = g >> 10;
    if (t < KK) {
      int n = idx[(size_t)g * KK + t];
      const float* p = x + ((size_t)b * NN + n) * 3;
      feat[t][0] = p[0] - cent[3 * g];
      feat[t][1] = p[1] - cent[3 * g + 1];
      feat[t][2] = p[2] - cent[3 * g + 2];
      const float* q = pts + ((size_t)b * NN + n) * 3;
      feat[t][3] = q[0];
      feat[t][4] = q[1];
      feat[t][5] = q[2];
    }
    __syncthreads();  // (A) feat ready; w2s ready (first iter); vT/mx reusable
    for (int k = kq * 8; k < kq * 8 + 8; ++k) {
      float a = bias1;
#pragma unroll
      for (int j = 0; j < 6; ++j) a += w1r[j] * feat[k][j];
      vT[c1][k] = fmaxf(0.f, a * scale1 + shift1);
    }
    __syncthreads();  // (B) vT ready
    float accA[8] = {0, 0, 0, 0, 0, 0, 0, 0};
    float accB[8] = {0, 0, 0, 0, 0, 0, 0, 0};
#pragma unroll
    for (int c0 = 0; c0 < 64; c0 += 4) {
      float4 wa4 = *(const float4*)&w2sA[c2p][c0];
      float4 wb4 = *(const float4*)&w2sB[c2p][c0];
#pragma unroll
      for (int cc = 0; cc < 4; ++cc) {
        int c = c0 + cc;
        float4 v0 = *(const float4*)&vT[c][ks * 8];
        float4 v1 = *(const float4*)&vT[c][ks * 8 + 4];
        float wa = (cc == 0 ? wa4.x : cc == 1 ? wa4.y : cc == 2 ? wa4.z : wa4.w);
        float wb = (cc == 0 ? wb4.x : cc == 1 ? wb4.y : cc == 2 ? wb4.z : wb4.w);
        accA[0] += wa * v0.x; accA[1] += wa * v0.y; accA[2] += wa * v0.z; accA[3] += wa * v0.w;
        accA[4] += wa * v1.x; accA[5] += wa * v1.y; accA[6] += wa * v1.z; accA[7] += wa * v1.w;
        accB[0] += wb * v0.x; accB[1] += wb * v0.y; accB[2] += wb * v0.z; accB[3] += wb * v0.w;
        accB[4] += wb * v1.x; accB[5] += wb * v1.y; accB[6] += wb * v1.z; accB[7] += wb * v1.w;
      }
    }
    float mA = -1e30f, mB = -1e30f, nA = 1e30f, nB = 1e30f;
#pragma unroll
    for (int i = 0; i < 8; ++i) {
      float a = accA[i] + bias2a;
      sumA += a; sqA += a * a;
      mA = fmaxf(mA, a); nA = fminf(nA, a);
      float c_ = accB[i] + bias2b;
      sumB += c_; sqB += c_ * c_;
      mB = fmaxf(mB, c_); nB = fminf(nB, c_);
    }
    mx[c2p][ks] = mA;      mn[c2p][ks] = nA;
    mx[c2p + 64][ks] = mB; mn[c2p + 64][ks] = nB;
    __syncthreads();  // (C) mx/mn ready
    if (t < C3) {
      float M = fmaxf(fmaxf(mx[t][0], mx[t][1]), fmaxf(mx[t][2], mx[t][3]));
      float m_ = fminf(fminf(mn[t][0], mn[t][1]), fminf(mn[t][2], mn[t][3]));
      gmax[(size_t)g * C3 + t] = M;
      gmin[(size_t)g * C3 + t] = m_;
    }
  }
  red[c2p][ks][0] = sumA;      red[c2p][ks][1] = sqA;
  red[c2p + 64][ks][0] = sumB; red[c2p + 64][ks][1] = sqB;
  __syncthreads();
  if (t < C3) {
    float s = ((red[t][0][0] + red[t][1][0]) + red[t][2][0]) + red[t][3][0];
    float q = ((red[t][0][1] + red[t][1][1]) + red[t][2][1]) + red[t][3][1];
    partial2[(size_t)(blockIdx.x * 128 + t) * 2] = s;
    partial2[(size_t)(blockIdx.x * 128 + t) * 2 + 1] = q;
  }
}

// ---------------- finalize BN2 scale/shift (8-way parallel over blocks) ----------------
__global__ void k_red2(const float* __restrict__ partial2,
                       const float* __restrict__ gamma, const float* __restrict__ beta,
                       float* __restrict__ sc2) {
  __shared__ double rd[128][8][2];
  int t = threadIdx.x;  // 1024
  int c = t & 127, q = t >> 7;  // q in 0..7
  double s = 0.0, qq = 0.0;
  for (int blk = q * 256; blk < q * 256 + 256; ++blk) {
    s += partial2[(size_t)(blk * 128 + c) * 2];
    qq += partial2[(size_t)(blk * 128 + c) * 2 + 1];
  }
  rd[c][q][0] = s; rd[c][q][1] = qq;
  __syncthreads();
  if (t < 128) {
    double S = 0.0, Q = 0.0;
#pragma unroll
    for (int i = 0; i < 8; ++i) { S += rd[t][i][0]; Q += rd[t][i][1]; }
    const double cnt = (double)BB * KK * SS;
    double mean = S / cnt;
    double var = Q / cnt - mean * mean;
    float scale = gamma[t] * (float)(1.0 / sqrt(var + 1e-5));
    float shift = beta[t] - (float)mean * scale;
    sc2[t] = scale;
    sc2[128 + t] = shift;
  }
}

// -------- final: affine+relu on the pooled pre-BN max (min if scale<0) --------
// max_k relu(a_k*s+t) == relu((s>=0 ? max_k a : min_k a)*s+t)  exactly (monotone f32 ops)
__global__ void k_final2(const float* __restrict__ gmin,
                         const float* __restrict__ sc2, float* __restrict__ outp) {
  int i = blockIdx.x * blockDim.x + threadIdx.x;  // over BB*SS*C3, gmax lives in outp
  if (i >= BB * SS * C3) return;
  int c = i & (C3 - 1);
  float scale = sc2[c], shift = sc2[C3 + c];
  float a = (scale >= 0.f) ? outp[i] : gmin[i];
  outp[i] = fmaxf(0.f, a * scale + shift);
}

extern "C" void kernel_launch(void* const* d_in, const int* in_sizes, int n_in,
                              void* d_out, int out_size, void* d_ws, size_t ws_size,
                              hipStream_t stream) {
  const float* x      = (const float*)d_in[0];
  const float* pts    = (const float*)d_in[1];
  const float* w1     = (const float*)d_in[2];
  const float* b1     = (const float*)d_in[3];
  const float* gamma1 = (const float*)d_in[4];
  const float* beta1  = (const float*)d_in[5];
  const float* w2     = (const float*)d_in[6];
  const float* b2     = (const float*)d_in[7];
  const float* gamma2 = (const float*)d_in[8];
  const float* beta2  = (const float*)d_in[9];

  float* out_cent = (float*)d_out;                       // [B,S,3]
  float* out_feat = (float*)d_out + (size_t)BB * SS * 3; // [B,S,128] (doubles as gmax)

  char* w = (char*)d_ws;
  float* aa    = (float*)w; w += (size_t)BB * SS * 4;
  int* idx     = (int*)w;   w += (size_t)BB * SS * KK * 4;
  float* p1    = (float*)w; w += (size_t)STAT_BLOCKS * 64 * 2 * 4;
  float* p2    = (float*)w; w += (size_t)STAT_BLOCKS * 128 * 2 * 4;
  float* sc1   = (float*)w; w += 64 * 2 * 4;
  float* sc2   = (float*)w; w += 128 * 2 * 4;
  float* gmin  = (float*)w; w += (size_t)BB * SS * C3 * 4;  // 8 MB

  k_fps<<<BB, 256, 0, stream>>>(x, out_cent, aa);
  k_ballstats1<<<STAT_BLOCKS, 256, 0, stream>>>(x, pts, out_cent, aa, w1, b1,
                                                idx, p1);
  k_red1<<<1, 1024, 0, stream>>>(p1, gamma1, beta1, sc1);
  k_stats2<<<STAT_BLOCKS, 256, 0, stream>>>(x, pts, out_cent, idx, w1, b1, sc1,
                                            w2, b2, p2, out_feat, gmin);
  k_red2<<<1, 1024, 0, stream>>>(p2, gamma2, beta2, sc2);
  k_final2<<<(BB * SS * C3 + 255) / 256, 256, 0, stream>>>(gmin, sc2, out_feat);
}